// Round 4
// baseline (297.010 us; speedup 1.0000x reference)
//
#include <hip/hip_runtime.h>

#define SS   2048
#define HQ   16
#define HK   2
#define GQ   8      // Hq/Hk
#define DD   128
#define DV   128
#define KS   32
#define ST   16
#define SELB 64
#define TOPN 16
#define WINW 512
#define TT   127    // (S-KS)/ST + 1
#define NSEL 32     // S/SEL
#define QSC  0.12751744f   // (1/sqrt(128)) * log2(e): fold scale+base-2 into Q fragments

typedef __attribute__((ext_vector_type(8))) short bf16x8;
typedef __attribute__((ext_vector_type(4))) float f32x4;

// exp2 fast path: v_exp_f32 is base-2 natively
#if defined(__has_builtin)
#  if __has_builtin(__builtin_amdgcn_exp2f)
#    define EXP2(x) __builtin_amdgcn_exp2f(x)
#  endif
#endif
#ifndef EXP2
#  define EXP2(x) __expf((x) * 0.6931471805599453f)
#endif

__device__ __forceinline__ short f2bf(float x) {
    union { float f; unsigned u; } a; a.f = x;
    unsigned r = a.u + 0x7FFFu + ((a.u >> 16) & 1u);
    return (short)(r >> 16);
}
__device__ __forceinline__ float bf2f(short b) {
    union { unsigned u; float f; } x; x.u = ((unsigned)(unsigned short)b) << 16; return x.f;
}

// ---------------- kernel 0: prep — emit MFMA-fragment-ordered arrays ----------------
// Layouts (all hot-loop loads in k_fused are base + lane*16B, fully coalesced):
//  kfr [n][tb(128)][kb(4)][lane(64)][8]  : K A-frag,  token=tb*16+l16, feat=kb*32+quad*8+e
//  vfr [n][cb(32)][h(2)][f(8)][lane][8]  : V B-frag,  d=f*16+l16, tok=cb*64+h*32+quad*8+e
//  ckh/ckl [n][tile(8)][kb(4)][lane][8]  : cmpK hi/lo A-frag, t=tile*16+l16 (t>=TT pad 0)
//  cvfr [n][w(4)][half(2)][kb(4)][lane][8]: cmpV B-frag, d=w*32+half*16+l16, tok=kb*32+quad*8+e
//  wgh/wgl [kb(4)][lane(64)][8]          : gate-weight A-frag hi/lo, row c=l16 (<3), k=kb*32+quad*8+e
__global__ __launch_bounds__(256) void k_prep(
    const float* __restrict__ k, const float* __restrict__ v,
    const float* __restrict__ wck, const float* __restrict__ wcv,
    const float* __restrict__ wg,
    short* __restrict__ kfr, short* __restrict__ vfr,
    short* __restrict__ ckh, short* __restrict__ ckl,
    short* __restrict__ cvfr, short* __restrict__ wgh, short* __restrict__ wgl)
{
    __shared__ float red[256];
    int bid = blockIdx.x, tid = threadIdx.x;
    int lane = tid & 63, quad = (lane >> 4) & 3, l16 = lane & 15;
    if (bid < 256) {
        // K fragments: one block per (tb, n)
        int tb = bid >> 1, n = bid & 1;
        int kb = tid >> 6;
        int token = tb * 16 + l16;
        int feat = kb * 32 + quad * 8;
        const float* src = &k[(token * HK + n) * DD + feat];
        bf16x8 t;
        #pragma unroll
        for (int e = 0; e < 8; ++e) t[e] = f2bf(src[e]);
        *(bf16x8*)&kfr[(((n * 128 + tb) * 4 + kb) * 64 + lane) * 8] = t;
    } else if (bid < 512) {
        // V fragments: one block per (cb, n, it)
        int id = bid - 256;
        int cb = id >> 3, n = (id >> 2) & 1, it = id & 3;
        int frag = it * 4 + (tid >> 6);
        int h = frag >> 3, f = frag & 7;
        int d = f * 16 + l16;
        int tok0 = cb * 64 + h * 32 + quad * 8;
        bf16x8 t;
        #pragma unroll
        for (int e = 0; e < 8; ++e) t[e] = f2bf(v[((tok0 + e) * HK + n) * DV + d]);
        *(bf16x8*)&vfr[((((n * 32 + cb) * 2 + h) * 8 + f) * 64 + lane) * 8] = t;
    } else if (bid < 768) {
        // cmpK hi/lo: one block per (n,t); 256 threads = (d, j-half)
        int id = bid - 512;
        int n = id & 1, t = id >> 1;      // t in [0,128)
        int d = tid & 127, jh = tid >> 7;
        float a = 0.f;
        if (t < TT) {
            #pragma unroll
            for (int jj = 0; jj < 16; ++jj) {
                int j = jh * 16 + jj;
                a += k[((t * ST + j) * HK + n) * DD + d] * wck[j];
            }
        }
        red[tid] = a;
        __syncthreads();
        if (tid < 128) {
            float s = red[tid] + red[tid + 128];
            short hi = f2bf(s);
            short lo = f2bf(s - bf2f(hi));
            int tile = t >> 4, l16i = t & 15;
            int kb = d >> 5, qd = (d >> 3) & 3, e = d & 7;
            int off = (((n * 8 + tile) * 4 + kb) * 64 + qd * 16 + l16i) * 8 + e;
            ckh[off] = hi;
            ckl[off] = lo;
        }
    } else if (bid < 1024) {
        // cmpV: one block per (n,tok); 256 threads = (d, j-half)
        int id = bid - 768;
        int n = id & 1, tok = id >> 1;    // tok in [0,128)
        int d = tid & 127, jh = tid >> 7;
        float a = 0.f;
        if (tok < TT) {
            #pragma unroll
            for (int jj = 0; jj < 16; ++jj) {
                int j = jh * 16 + jj;
                a += v[((tok * ST + j) * HK + n) * DV + d] * wcv[j];
            }
        }
        red[tid] = a;
        __syncthreads();
        if (tid < 128) {
            float s = red[tid] + red[tid + 128];
            int w2 = d >> 5, half = (d >> 4) & 1, l16i = d & 15;
            int kb = tok >> 5, qd = (tok >> 3) & 3, e = tok & 7;
            cvfr[((((n * 4 + w2) * 2 + half) * 4 + kb) * 64 + qd * 16 + l16i) * 8 + e] = f2bf(s);
        }
    } else {
        // gate-weight fragments: wg[128][3] -> A-frag hi/lo (lane l16 = output col c)
        int kb = tid >> 6;
        bf16x8 th, tl;
        #pragma unroll
        for (int e = 0; e < 8; ++e) {
            int kidx = kb * 32 + quad * 8 + e;
            float x = (l16 < 3) ? wg[kidx * 3 + l16] : 0.f;
            th[e] = f2bf(x);
            tl[e] = f2bf(x - bf2f(th[e]));
        }
        *(bf16x8*)&wgh[(kb * 64 + lane) * 8] = th;
        *(bf16x8*)&wgl[(kb * 64 + lane) * 8] = tl;
    }
}

// ---------------- fused kernel: cmp attention + selection + flash (no-max softmax) ----------------
__global__ __launch_bounds__(256, 8) void k_fused(
    const float* __restrict__ q,
    const short* __restrict__ ckh, const short* __restrict__ ckl,
    const short* __restrict__ cvfr,
    const short* __restrict__ kfr, const short* __restrict__ vfr,
    const short* __restrict__ wgh, const short* __restrict__ wgl,
    const float* __restrict__ bg,
    float* __restrict__ out)
{
    int s0 = (SS - 2) - (int)blockIdx.x * 2;   // heavy-first
    int s1 = s0 + 1;
    int n = blockIdx.y;
    int tid = threadIdx.x;
    int w = tid >> 6, lane = tid & 63, quad = lane >> 4, l16 = lane & 15;

    // LDS plan (~18 KB -> 8 blocks/CU = 32 waves, grid 2048 = 256*8 packs with zero tail):
    //  p  (phases 2-5) | Pw (run_chunks) | o2 (combine, two-pass halves) share one union.
    __shared__ union {
        float p[16][132];      // 8.25 KB (pad kills 16-way write conflict)
        short Pw[4][16][64];   // 8 KB per-wave P tile, XOR-swizzled chunks
        float o2[2][16][68];   // 8.5 KB combine tree scratch (d-half at a time)
    } u;
    __shared__ short OselB[16][128];   // 4 KB (written combine(true), read at end)
    __shared__ short cmpO[16][136];
    __shared__ float g3v[16][3];
    __shared__ float pslc2[2][NSEL];
    __shared__ float lw[4][16];
    __shared__ unsigned selMask[2];
    __shared__ unsigned ublk[NSEL];
    __shared__ int shUCnt;

    f32x4 z4 = {0.f, 0.f, 0.f, 0.f};
    const bf16x8 ones8 = {0x3F80, 0x3F80, 0x3F80, 0x3F80, 0x3F80, 0x3F80, 0x3F80, 0x3F80};

    // ---- phase 1+2: qb (hi/lo) fragments (pre-scaled by QSC) direct from global ----
    bf16x8 qb[4];
    bf16x8 qlb[4];
    {
        const float* qpg = &q[((s0 + (l16 >> 3)) * HQ + n * GQ + (l16 & 7)) * DD + quad * 8];
        #pragma unroll
        for (int kb = 0; kb < 4; ++kb) {
            f32x4 x = *(const f32x4*)(qpg + kb * 32);
            f32x4 y = *(const f32x4*)(qpg + kb * 32 + 4);
            bf16x8 th, tl;
            #pragma unroll
            for (int j = 0; j < 4; ++j) {
                float xs = x[j] * QSC, ys = y[j] * QSC;
                th[j] = f2bf(xs);     tl[j] = f2bf(xs - bf2f(th[j]));
                th[4+j] = f2bf(ys);   tl[4+j] = f2bf(ys - bf2f(th[4+j]));
            }
            qb[kb] = th; qlb[kb] = tl;
        }
    }
    // gate via MFMA on wave 0: C[row=c from wg-frag][col=h2 from qb]; descale by 1/QSC
    if (w == 0) {
        f32x4 gacc = z4;
        #pragma unroll
        for (int kb = 0; kb < 4; ++kb) {
            bf16x8 wh = *(const bf16x8*)&wgh[(kb * 64 + lane) * 8];
            bf16x8 wl = *(const bf16x8*)&wgl[(kb * 64 + lane) * 8];
            gacc = __builtin_amdgcn_mfma_f32_16x16x32_bf16(wh, qb[kb], gacc, 0, 0, 0);
            gacc = __builtin_amdgcn_mfma_f32_16x16x32_bf16(wl, qb[kb], gacc, 0, 0, 0);
            gacc = __builtin_amdgcn_mfma_f32_16x16x32_bf16(wh, qlb[kb], gacc, 0, 0, 0);
        }
        if (quad == 0) {
            #pragma unroll
            for (int r = 0; r < 3; ++r) {
                float a = gacc[r] * (1.f / QSC) + bg[r];
                g3v[l16][r] = 1.f / (1.f + __expf(-a));
            }
        }
    }
    // cmp scores: 2 tiles/wave, fragment loads are lane-coalesced (scores in log2 domain)
    for (int tile = w; tile < 8; tile += 4) {
        const short* khp = &ckh[((n * 8 + tile) * 256 + lane) * 8];
        const short* klp = &ckl[((n * 8 + tile) * 256 + lane) * 8];
        f32x4 acc = z4;
        #pragma unroll
        for (int kb = 0; kb < 4; ++kb) {
            bf16x8 ah = *(const bf16x8*)(khp + kb * 512);
            bf16x8 al = *(const bf16x8*)(klp + kb * 512);
            acc = __builtin_amdgcn_mfma_f32_16x16x32_bf16(ah, qb[kb], acc, 0, 0, 0);
            acc = __builtin_amdgcn_mfma_f32_16x16x32_bf16(al, qb[kb], acc, 0, 0, 0);
            acc = __builtin_amdgcn_mfma_f32_16x16x32_bf16(ah, qlb[kb], acc, 0, 0, 0);
        }
        *(f32x4*)&u.p[l16][tile * 16 + quad * 4] = acc;
    }
    __syncthreads();

    int ntt0 = (s0 >= KS - 1) ? min((s0 - (KS - 1)) / ST + 1, TT) : 0;
    int ntt1 = (s1 >= KS - 1) ? min((s1 - (KS - 1)) / ST + 1, TT) : 0;

    // ---- phase 3: cmp softmax (4 rows per wave, exact max-based path, base-2) ----
    #pragma unroll
    for (int rr = 0; rr < 4; ++rr) {
        int row = w * 4 + rr;
        int ntt = (row < 8) ? ntt0 : ntt1;
        int t1 = lane, t2 = lane + 64;
        float v1 = (t1 < ntt) ? u.p[row][t1] : -1e30f;
        float v2 = (t2 < ntt) ? u.p[row][t2] : -1e30f;
        float m = fmaxf(v1, v2);
        #pragma unroll
        for (int o = 32; o > 0; o >>= 1) m = fmaxf(m, __shfl_xor(m, o, 64));
        float e1 = (t1 < ntt) ? EXP2(v1 - m) : 0.f;
        float e2 = (t2 < ntt) ? EXP2(v2 - m) : 0.f;
        float ssum = e1 + e2;
        #pragma unroll
        for (int o = 32; o > 0; o >>= 1) ssum += __shfl_xor(ssum, o, 64);
        float inv = (ntt > 0) ? (1.f / ssum) : 0.f;
        e1 *= inv; e2 *= inv;
        u.p[row][t1] = e1; u.p[row][t2] = e2;
    }
    __syncthreads();

    // ---- phase 4: selection-block scores ----
    if (tid < 64) {
        int p01 = tid >> 5, m = tid & 31;
        float a = 0.f;
        for (int dt = -1; dt < 4; ++dt) {
            int t = 4 * m + dt;
            if (t < 0 || t >= TT) continue;
            bool maps = (t / 4 == m) || ((t % 4 == 3) && (t / 4 == m - 1));
            if (!maps) continue;
            for (int g = 0; g < GQ; ++g) a += u.p[p01 * 8 + g][t];
        }
        pslc2[p01][m] = a;
    }
    __syncthreads();

    // ---- phase 5: top-k (waves 0,1) + cmp PV via MFMA (all waves, P from fp32 p) ----
    if (w < 2) {
        int p01 = w;
        int sp = p01 ? s1 : s0;
        int cur = sp / SELB;
        float v;
        if (lane < NSEL) {
            int m = lane;
            if (m == 0 || m == cur) v = 1e30f;
            else if (m * SELB <= sp) v = pslc2[p01][m];
            else v = -1e30f;
        } else v = -1e31f;
        unsigned msk = 0;
        #pragma unroll
        for (int pick = 0; pick < TOPN; ++pick) {
            float bv = v;
            #pragma unroll
            for (int o = 32; o > 0; o >>= 1) bv = fmaxf(bv, __shfl_xor(bv, o, 64));
            unsigned long long b = __ballot(v == bv);
            int best = __ffsll((long long)b) - 1;
            if (bv > -5e29f) msk |= 1u << best;
            if (lane == best) v = -1e31f;
        }
        if (lane == 0) selMask[p01] = msk;
    }
    {
        f32x4 o0 = z4, o1 = z4;
        int d0 = w * 32 + l16;
        const short* cvp = &cvfr[((n * 4 + w) * 512 + lane) * 8];   // half=0,kb=0 base
        const float* prow = &u.p[l16][quad * 8];
        #pragma unroll
        for (int kb = 0; kb < 4; ++kb) {
            f32x4 x = *(const f32x4*)(prow + kb * 32);
            f32x4 y = *(const f32x4*)(prow + kb * 32 + 4);
            bf16x8 pa;
            #pragma unroll
            for (int j = 0; j < 4; ++j) { pa[j] = f2bf(x[j]); pa[4+j] = f2bf(y[j]); }
            bf16x8 vb0 = *(const bf16x8*)(cvp + kb * 512);
            bf16x8 vb1 = *(const bf16x8*)(cvp + 2048 + kb * 512);
            o0 = __builtin_amdgcn_mfma_f32_16x16x32_bf16(pa, vb0, o0, 0, 0, 0);
            o1 = __builtin_amdgcn_mfma_f32_16x16x32_bf16(pa, vb1, o1, 0, 0, 0);
        }
        #pragma unroll
        for (int r = 0; r < 4; ++r) {
            int h2 = quad * 4 + r;
            cmpO[h2][d0]      = f2bf(o0[r]);
            cmpO[h2][d0 + 16] = f2bf(o1[r]);
        }
    }
    __syncthreads();

    // ---- phase 6: build union block list ----
    if (tid == 0) {
        unsigned m0 = selMask[0], m1 = selMask[1], mu = m0 | m1;
        int uc = 0;
        for (int b = 0; b < NSEL; ++b)
            if ((mu >> b) & 1u)
                ublk[uc++] = (unsigned)(b * SELB) | (((m0 >> b) & 1u) << 30) | (((m1 >> b) & 1u) << 31);
        shUCnt = uc;
    }
    __syncthreads();
    int uCnt = shUCnt;
    int j00 = (s0 >= WINW) ? (s0 - WINW) : 0;
    int j01 = (s1 >= WINW) ? (s1 - WINW) : 0;
    int tb0 = j00 & ~63;
    int nBlkB = ((s1 - tb0) >> 6) + 1;

    int sLim = (l16 < 8) ? s0 : s1;
    f32x4 o[8];
    f32x4 lacc;

    // swizzled Pw base for this lane's row (l16); 16B-chunk index XORed with (l16&7)
    char* pwRow = (char*)&u.Pw[w][l16][0];
    int swz = l16 & 7;

    // ---- flash chunk loop: coalesced fragment loads, cheap mask, trunc pack ----
    auto run_chunks = [&](int nB, bool selMode) {
        #pragma unroll
        for (int f = 0; f < 8; ++f) o[f] = z4;
        lacc = z4;
        int loWin = selMode ? 0 : ((l16 < 8) ? j00 : j01);
        for (int bi = w; bi < nB; bi += 4) {
            int tstart, vis;
            if (selMode) {
                unsigned e = ublk[bi];
                tstart = (int)(e & 0x0FFFFFFFu);
                vis = (l16 < 8) ? (int)((e >> 30) & 1u) : (int)(e >> 31);
            } else {
                tstart = tb0 + bi * 64;
                vis = 1;
            }
            // scores: 4 token-tiles of 16; K fragments coalesced (log2 domain)
            f32x4 a4[4] = {z4, z4, z4, z4};
            {
                const short* kp = &kfr[((n * 128 + (tstart >> 4)) * 256 + lane) * 8];
                bf16x8 kf[2][4];
                #pragma unroll
                for (int t2 = 0; t2 < 2; ++t2)
                    #pragma unroll
                    for (int kb = 0; kb < 4; ++kb)
                        kf[t2][kb] = *(const bf16x8*)(kp + (t2 * 4 + kb) * 512);
                #pragma unroll
                for (int kb = 0; kb < 4; ++kb) {
                    a4[0] = __builtin_amdgcn_mfma_f32_16x16x32_bf16(kf[0][kb], qb[kb], a4[0], 0, 0, 0);
                    a4[1] = __builtin_amdgcn_mfma_f32_16x16x32_bf16(kf[1][kb], qb[kb], a4[1], 0, 0, 0);
                }
                #pragma unroll
                for (int t2 = 0; t2 < 2; ++t2)
                    #pragma unroll
                    for (int kb = 0; kb < 4; ++kb)
                        kf[t2][kb] = *(const bf16x8*)(kp + ((2 + t2) * 4 + kb) * 512);
                #pragma unroll
                for (int kb = 0; kb < 4; ++kb) {
                    a4[2] = __builtin_amdgcn_mfma_f32_16x16x32_bf16(kf[0][kb], qb[kb], a4[2], 0, 0, 0);
                    a4[3] = __builtin_amdgcn_mfma_f32_16x16x32_bf16(kf[1][kb], qb[kb], a4[3], 0, 0, 0);
                }
            }
            // V first-half prefetch (coalesced fragments)
            const short* vp = &vfr[((n * 32 + (tstart >> 6)) * 1024 + lane) * 8];
            bf16x8 vf[8];
            #pragma unroll
            for (int f = 0; f < 8; ++f) vf[f] = *(const bf16x8*)(vp + f * 512);
            // mask via unsigned-range: valid iff (unsigned)(tloc-lo) < rng; P = 2^a4
            {
                int lo = loWin - tstart;
                int hi = vis ? (sLim - tstart) : (lo - 1);
                int rngS = hi - lo + 1;
                unsigned rng = (unsigned)(rngS > 0 ? rngS : 0);
                int tb = quad * 4 - lo;
                #pragma unroll
                for (int tile = 0; tile < 4; ++tile) {
                    float ev[4];
                    #pragma unroll
                    for (int r = 0; r < 4; ++r) {
                        unsigned uu = (unsigned)(tb + tile * 16 + r);
                        float ex = EXP2(a4[tile][r]);
                        ev[r] = (uu < rng) ? ex : 0.f;
                    }
                    // truncation pack (floor to bf16): 2 ops/pair vs ~5 for RNE
                    unsigned plo = (__float_as_uint(ev[1]) & 0xFFFF0000u) | (__float_as_uint(ev[0]) >> 16);
                    unsigned phi = (__float_as_uint(ev[3]) & 0xFFFF0000u) | (__float_as_uint(ev[2]) >> 16);
                    uint2 pk; pk.x = plo; pk.y = phi;
                    // logical 8B slot: byte = tile*32 + quad*8 -> chunk = tile*2+(quad>>1), half = quad&1
                    int chunk = (tile * 2 + (quad >> 1)) ^ swz;
                    *(uint2*)(pwRow + chunk * 16 + (quad & 1) * 8) = pk;
                }
            }
            __builtin_amdgcn_s_waitcnt(0xC07F);   // lgkmcnt(0): drain Pw writes
            bf16x8 pa0 = *(const bf16x8*)(pwRow + ((quad ^ swz) * 16));
            bf16x8 pa1 = *(const bf16x8*)(pwRow + (((4 + quad) ^ swz) * 16));
            // row-sums via ones-MFMA: lacc[r] = sum_k P[quad*4+r][k] (replaces 12+ VALU adds)
            lacc = __builtin_amdgcn_mfma_f32_16x16x32_bf16(pa0, ones8, lacc, 0, 0, 0);
            lacc = __builtin_amdgcn_mfma_f32_16x16x32_bf16(pa1, ones8, lacc, 0, 0, 0);
            #pragma unroll
            for (int f = 0; f < 8; ++f)
                o[f] = __builtin_amdgcn_mfma_f32_16x16x32_bf16(pa0, vf[f], o[f], 0, 0, 0);
            #pragma unroll
            for (int f = 0; f < 8; ++f)
                o[f] = __builtin_amdgcn_mfma_f32_16x16x32_bf16(pa1, *(const bf16x8*)(vp + (8 + f) * 512), o[f], 0, 0, 0);
        }
    };

    // ---- combine: plain sums (no rescale), 2-step tree over two d-halves ----
    auto combine = [&](bool isA) {
        // lacc[r] holds full row-sum for row quad*4+r (replicated over l16 cols)
        if (l16 == 0) {
            #pragma unroll
            for (int r = 0; r < 4; ++r) lw[w][quad * 4 + r] = lacc[r];
        }
        __syncthreads();   // all chunk loops done; Pw region dead; lw ready
        float ltot = lw[0][l16] + lw[1][l16] + lw[2][l16] + lw[3][l16];
        float linv = 1.f / ltot;
        float linvr[4];
        #pragma unroll
        for (int r = 0; r < 4; ++r) linvr[r] = __shfl(linv, quad * 4 + r, 64);
        #pragma unroll
        for (int half = 0; half < 2; ++half) {
            if (w >= 2) {
                #pragma unroll
                for (int f = 0; f < 4; ++f)
                    #pragma unroll
                    for (int r = 0; r < 4; ++r)
                        u.o2[w - 2][quad * 4 + r][l16 + 16 * f] = o[half * 4 + f][r];
            }
            __syncthreads();
            if (w < 2) {
                #pragma unroll
                for (int f = 0; f < 4; ++f)
                    #pragma unroll
                    for (int r = 0; r < 4; ++r)
                        o[half * 4 + f][r] += u.o2[w][quad * 4 + r][l16 + 16 * f];
            }
            __syncthreads();
            if (w == 1) {
                #pragma unroll
                for (int f = 0; f < 4; ++f)
                    #pragma unroll
                    for (int r = 0; r < 4; ++r)
                        u.o2[0][quad * 4 + r][l16 + 16 * f] = o[half * 4 + f][r];
            }
            __syncthreads();
            if (w == 0) {
                #pragma unroll
                for (int f = 0; f < 4; ++f)
                    #pragma unroll
                    for (int r = 0; r < 4; ++r)
                        o[half * 4 + f][r] += u.o2[0][quad * 4 + r][l16 + 16 * f];
                if (isA) {
                    #pragma unroll
                    for (int f = 0; f < 4; ++f)
                        #pragma unroll
                        for (int r = 0; r < 4; ++r)
                            OselB[quad * 4 + r][l16 + 16 * (half * 4 + f)] = f2bf(o[half * 4 + f][r] * linvr[r]);
                } else {
                    #pragma unroll
                    for (int f = 0; f < 4; ++f)
                        #pragma unroll
                        for (int r = 0; r < 4; ++r) {
                            int h2 = quad * 4 + r;
                            int p = h2 >> 3, g = h2 & 7;
                            int d = l16 + 16 * (half * 4 + f);
                            int ob = ((s0 + p) * HQ + n * GQ + g) * DV + d;
                            float owin = o[half * 4 + f][r] * linvr[r];
                            out[ob] = g3v[h2][0] * bf2f(cmpO[h2][d]) + g3v[h2][1] * bf2f(OselB[h2][d]) + g3v[h2][2] * owin;
                        }
                }
            }
            __syncthreads();   // scratch free before next half / next pass's Pw writes
        }
    };

    run_chunks(uCnt, true);
    combine(true);
    run_chunks(nBlkB, false);
    combine(false);
}

extern "C" void kernel_launch(void* const* d_in, const int* in_sizes, int n_in,
                              void* d_out, int out_size, void* d_ws, size_t ws_size,
                              hipStream_t stream) {
    const float* q   = (const float*)d_in[0];
    const float* k   = (const float*)d_in[1];
    const float* v   = (const float*)d_in[2];
    const float* wck = (const float*)d_in[3];
    const float* wcv = (const float*)d_in[4];
    const float* wg  = (const float*)d_in[5];
    const float* bg  = (const float*)d_in[6];
    float* out = (float*)d_out;

    short* kfr  = (short*)d_ws;                  // 2*128*4*64*8 shorts (1 MB)
    short* vfr  = kfr + 2 * 128 * 4 * 64 * 8;    // 2*32*2*8*64*8 shorts (1 MB)
    short* ckh  = vfr + 2 * 32 * 2 * 8 * 64 * 8; // 2*8*4*64*8 shorts (64 KB)
    short* ckl  = ckh + 2 * 8 * 4 * 64 * 8;      // 64 KB
    short* cvfr = ckl + 2 * 8 * 4 * 64 * 8;      // 2*4*2*4*64*8 shorts (64 KB)
    short* wgh  = cvfr + 2 * 4 * 2 * 4 * 64 * 8; // 4*64*8 shorts (4 KB)
    short* wgl  = wgh + 4 * 64 * 8;              // 4 KB

    k_prep<<<1025, 256, 0, stream>>>(k, v, wck, wcv, wg, kfr, vfr, ckh, ckl, cvfr, wgh, wgl);
    k_fused<<<dim3(SS / 2, HK), 256, 0, stream>>>(q, ckh, ckl, cvfr, kfr, vfr, wgh, wgl, bg, out);
}

// Round 5
// 164.219 us; speedup vs baseline: 1.8086x; 1.8086x over previous
//
#include <hip/hip_runtime.h>

#define SS   2048
#define HQ   16
#define HK   2
#define GQ   8      // Hq/Hk
#define DD   128
#define DV   128
#define KS   32
#define ST   16
#define SELB 64
#define TOPN 16
#define WINW 512
#define TT   127    // (S-KS)/ST + 1
#define NSEL 32     // S/SEL
#define QSC  0.12751744f   // (1/sqrt(128)) * log2(e): fold scale+base-2 into Q fragments

typedef __attribute__((ext_vector_type(8))) short bf16x8;
typedef __attribute__((ext_vector_type(4))) float f32x4;

// exp2 fast path: v_exp_f32 is base-2 natively
#if defined(__has_builtin)
#  if __has_builtin(__builtin_amdgcn_exp2f)
#    define EXP2(x) __builtin_amdgcn_exp2f(x)
#  endif
#endif
#ifndef EXP2
#  define EXP2(x) __expf((x) * 0.6931471805599453f)
#endif

__device__ __forceinline__ short f2bf(float x) {
    union { float f; unsigned u; } a; a.f = x;
    unsigned r = a.u + 0x7FFFu + ((a.u >> 16) & 1u);
    return (short)(r >> 16);
}
__device__ __forceinline__ float bf2f(short b) {
    union { unsigned u; float f; } x; x.u = ((unsigned)(unsigned short)b) << 16; return x.f;
}

// ---------------- kernel 0: prep — emit MFMA-fragment-ordered arrays ----------------
// Layouts (all hot-loop loads in k_fused are base + lane*16B, fully coalesced):
//  kfr [n][tb(128)][kb(4)][lane(64)][8]  : K A-frag,  token=tb*16+l16, feat=kb*32+quad*8+e
//  vfr [n][cb(32)][h(2)][f(8)][lane][8]  : V B-frag,  d=f*16+l16, tok=cb*64+h*32+quad*8+e
//  ckh/ckl [n][tile(8)][kb(4)][lane][8]  : cmpK hi/lo A-frag, t=tile*16+l16 (t>=TT pad 0)
//  cvfr [n][w(4)][half(2)][kb(4)][lane][8]: cmpV B-frag, d=w*32+half*16+l16, tok=kb*32+quad*8+e
//  wgh/wgl [kb(4)][lane(64)][8]          : gate-weight A-frag hi/lo, row c=l16 (<3), k=kb*32+quad*8+e
__global__ __launch_bounds__(256) void k_prep(
    const float* __restrict__ k, const float* __restrict__ v,
    const float* __restrict__ wck, const float* __restrict__ wcv,
    const float* __restrict__ wg,
    short* __restrict__ kfr, short* __restrict__ vfr,
    short* __restrict__ ckh, short* __restrict__ ckl,
    short* __restrict__ cvfr, short* __restrict__ wgh, short* __restrict__ wgl)
{
    __shared__ float red[256];
    int bid = blockIdx.x, tid = threadIdx.x;
    int lane = tid & 63, quad = (lane >> 4) & 3, l16 = lane & 15;
    if (bid < 256) {
        // K fragments: one block per (tb, n)
        int tb = bid >> 1, n = bid & 1;
        int kb = tid >> 6;
        int token = tb * 16 + l16;
        int feat = kb * 32 + quad * 8;
        const float* src = &k[(token * HK + n) * DD + feat];
        bf16x8 t;
        #pragma unroll
        for (int e = 0; e < 8; ++e) t[e] = f2bf(src[e]);
        *(bf16x8*)&kfr[(((n * 128 + tb) * 4 + kb) * 64 + lane) * 8] = t;
    } else if (bid < 512) {
        // V fragments: one block per (cb, n, it)
        int id = bid - 256;
        int cb = id >> 3, n = (id >> 2) & 1, it = id & 3;
        int frag = it * 4 + (tid >> 6);
        int h = frag >> 3, f = frag & 7;
        int d = f * 16 + l16;
        int tok0 = cb * 64 + h * 32 + quad * 8;
        bf16x8 t;
        #pragma unroll
        for (int e = 0; e < 8; ++e) t[e] = f2bf(v[((tok0 + e) * HK + n) * DV + d]);
        *(bf16x8*)&vfr[((((n * 32 + cb) * 2 + h) * 8 + f) * 64 + lane) * 8] = t;
    } else if (bid < 768) {
        // cmpK hi/lo: one block per (n,t); 256 threads = (d, j-half)
        int id = bid - 512;
        int n = id & 1, t = id >> 1;      // t in [0,128)
        int d = tid & 127, jh = tid >> 7;
        float a = 0.f;
        if (t < TT) {
            #pragma unroll
            for (int jj = 0; jj < 16; ++jj) {
                int j = jh * 16 + jj;
                a += k[((t * ST + j) * HK + n) * DD + d] * wck[j];
            }
        }
        red[tid] = a;
        __syncthreads();
        if (tid < 128) {
            float s = red[tid] + red[tid + 128];
            short hi = f2bf(s);
            short lo = f2bf(s - bf2f(hi));
            int tile = t >> 4, l16i = t & 15;
            int kb = d >> 5, qd = (d >> 3) & 3, e = d & 7;
            int off = (((n * 8 + tile) * 4 + kb) * 64 + qd * 16 + l16i) * 8 + e;
            ckh[off] = hi;
            ckl[off] = lo;
        }
    } else if (bid < 1024) {
        // cmpV: one block per (n,tok); 256 threads = (d, j-half)
        int id = bid - 768;
        int n = id & 1, tok = id >> 1;    // tok in [0,128)
        int d = tid & 127, jh = tid >> 7;
        float a = 0.f;
        if (tok < TT) {
            #pragma unroll
            for (int jj = 0; jj < 16; ++jj) {
                int j = jh * 16 + jj;
                a += v[((tok * ST + j) * HK + n) * DV + d] * wcv[j];
            }
        }
        red[tid] = a;
        __syncthreads();
        if (tid < 128) {
            float s = red[tid] + red[tid + 128];
            int w2 = d >> 5, half = (d >> 4) & 1, l16i = d & 15;
            int kb = tok >> 5, qd = (tok >> 3) & 3, e = tok & 7;
            cvfr[((((n * 4 + w2) * 2 + half) * 4 + kb) * 64 + qd * 16 + l16i) * 8 + e] = f2bf(s);
        }
    } else {
        // gate-weight fragments: wg[128][3] -> A-frag hi/lo (lane l16 = output col c)
        int kb = tid >> 6;
        bf16x8 th, tl;
        #pragma unroll
        for (int e = 0; e < 8; ++e) {
            int kidx = kb * 32 + quad * 8 + e;
            float x = (l16 < 3) ? wg[kidx * 3 + l16] : 0.f;
            th[e] = f2bf(x);
            tl[e] = f2bf(x - bf2f(th[e]));
        }
        *(bf16x8*)&wgh[(kb * 64 + lane) * 8] = th;
        *(bf16x8*)&wgl[(kb * 64 + lane) * 8] = tl;
    }
}

// ---------------- fused kernel: cmp attention + selection + flash (no-max softmax) ----------------
// NOTE: launch_bounds (256,4): round 4 proved (256,8) forces 64-total-reg allocation ->
// massive scratch spills (FETCH 17->364 MB). With 128-reg ceiling the compiler lands at
// ~64 VGPR, which ALLOWS 8 waves/SIMD anyway; LDS 18432 allows 8 blocks/CU.
__global__ __launch_bounds__(256, 4) void k_fused(
    const float* __restrict__ q,
    const short* __restrict__ ckh, const short* __restrict__ ckl,
    const short* __restrict__ cvfr,
    const short* __restrict__ kfr, const short* __restrict__ vfr,
    const short* __restrict__ wgh, const short* __restrict__ wgl,
    const float* __restrict__ bg,
    float* __restrict__ out)
{
    int s0 = (SS - 2) - (int)blockIdx.x * 2;   // heavy-first
    int s1 = s0 + 1;
    int n = blockIdx.y;
    int tid = threadIdx.x;
    int w = tid >> 6, lane = tid & 63, quad = lane >> 4, l16 = lane & 15;

    // LDS plan (~18 KB): p (phases 2-5) | Pw (run_chunks) | o2 (combine halves) share one union.
    __shared__ union {
        float p[16][132];      // 8.25 KB (pad kills 16-way write conflict)
        short Pw[4][16][64];   // 8 KB per-wave P tile, XOR-swizzled chunks
        float o2[2][16][68];   // 8.5 KB combine tree scratch (d-half at a time)
    } u;
    __shared__ short OselB[16][128];   // 4 KB (written combine(true), read at end)
    __shared__ short cmpO[16][136];
    __shared__ float g3v[16][3];
    __shared__ float pslc2[2][NSEL];
    __shared__ float lw[4][16];
    __shared__ unsigned selMask[2];
    __shared__ unsigned ublk[NSEL];
    __shared__ int shUCnt;

    f32x4 z4 = {0.f, 0.f, 0.f, 0.f};
    const bf16x8 ones8 = {0x3F80, 0x3F80, 0x3F80, 0x3F80, 0x3F80, 0x3F80, 0x3F80, 0x3F80};

    // ---- phase 1+2: qb (hi/lo) fragments (pre-scaled by QSC) direct from global ----
    bf16x8 qb[4];
    bf16x8 qlb[4];
    {
        const float* qpg = &q[((s0 + (l16 >> 3)) * HQ + n * GQ + (l16 & 7)) * DD + quad * 8];
        #pragma unroll
        for (int kb = 0; kb < 4; ++kb) {
            f32x4 x = *(const f32x4*)(qpg + kb * 32);
            f32x4 y = *(const f32x4*)(qpg + kb * 32 + 4);
            bf16x8 th, tl;
            #pragma unroll
            for (int j = 0; j < 4; ++j) {
                float xs = x[j] * QSC, ys = y[j] * QSC;
                th[j] = f2bf(xs);     tl[j] = f2bf(xs - bf2f(th[j]));
                th[4+j] = f2bf(ys);   tl[4+j] = f2bf(ys - bf2f(th[4+j]));
            }
            qb[kb] = th; qlb[kb] = tl;
        }
    }
    // gate via MFMA on wave 0: C[row=c from wg-frag][col=h2 from qb]; descale by 1/QSC
    if (w == 0) {
        f32x4 gacc = z4;
        #pragma unroll
        for (int kb = 0; kb < 4; ++kb) {
            bf16x8 wh = *(const bf16x8*)&wgh[(kb * 64 + lane) * 8];
            bf16x8 wl = *(const bf16x8*)&wgl[(kb * 64 + lane) * 8];
            gacc = __builtin_amdgcn_mfma_f32_16x16x32_bf16(wh, qb[kb], gacc, 0, 0, 0);
            gacc = __builtin_amdgcn_mfma_f32_16x16x32_bf16(wl, qb[kb], gacc, 0, 0, 0);
            gacc = __builtin_amdgcn_mfma_f32_16x16x32_bf16(wh, qlb[kb], gacc, 0, 0, 0);
        }
        if (quad == 0) {
            #pragma unroll
            for (int r = 0; r < 3; ++r) {
                float a = gacc[r] * (1.f / QSC) + bg[r];
                g3v[l16][r] = 1.f / (1.f + __expf(-a));
            }
        }
    }
    // cmp scores: 2 tiles/wave, fragment loads are lane-coalesced (scores in log2 domain)
    for (int tile = w; tile < 8; tile += 4) {
        const short* khp = &ckh[((n * 8 + tile) * 256 + lane) * 8];
        const short* klp = &ckl[((n * 8 + tile) * 256 + lane) * 8];
        f32x4 acc = z4;
        #pragma unroll
        for (int kb = 0; kb < 4; ++kb) {
            bf16x8 ah = *(const bf16x8*)(khp + kb * 512);
            bf16x8 al = *(const bf16x8*)(klp + kb * 512);
            acc = __builtin_amdgcn_mfma_f32_16x16x32_bf16(ah, qb[kb], acc, 0, 0, 0);
            acc = __builtin_amdgcn_mfma_f32_16x16x32_bf16(al, qb[kb], acc, 0, 0, 0);
            acc = __builtin_amdgcn_mfma_f32_16x16x32_bf16(ah, qlb[kb], acc, 0, 0, 0);
        }
        *(f32x4*)&u.p[l16][tile * 16 + quad * 4] = acc;
    }
    __syncthreads();

    int ntt0 = (s0 >= KS - 1) ? min((s0 - (KS - 1)) / ST + 1, TT) : 0;
    int ntt1 = (s1 >= KS - 1) ? min((s1 - (KS - 1)) / ST + 1, TT) : 0;

    // ---- phase 3: cmp softmax (4 rows per wave, exact max-based path, base-2) ----
    #pragma unroll
    for (int rr = 0; rr < 4; ++rr) {
        int row = w * 4 + rr;
        int ntt = (row < 8) ? ntt0 : ntt1;
        int t1 = lane, t2 = lane + 64;
        float v1 = (t1 < ntt) ? u.p[row][t1] : -1e30f;
        float v2 = (t2 < ntt) ? u.p[row][t2] : -1e30f;
        float m = fmaxf(v1, v2);
        #pragma unroll
        for (int o = 32; o > 0; o >>= 1) m = fmaxf(m, __shfl_xor(m, o, 64));
        float e1 = (t1 < ntt) ? EXP2(v1 - m) : 0.f;
        float e2 = (t2 < ntt) ? EXP2(v2 - m) : 0.f;
        float ssum = e1 + e2;
        #pragma unroll
        for (int o = 32; o > 0; o >>= 1) ssum += __shfl_xor(ssum, o, 64);
        float inv = (ntt > 0) ? (1.f / ssum) : 0.f;
        e1 *= inv; e2 *= inv;
        u.p[row][t1] = e1; u.p[row][t2] = e2;
    }
    __syncthreads();

    // ---- phase 4: selection-block scores ----
    if (tid < 64) {
        int p01 = tid >> 5, m = tid & 31;
        float a = 0.f;
        for (int dt = -1; dt < 4; ++dt) {
            int t = 4 * m + dt;
            if (t < 0 || t >= TT) continue;
            bool maps = (t / 4 == m) || ((t % 4 == 3) && (t / 4 == m - 1));
            if (!maps) continue;
            for (int g = 0; g < GQ; ++g) a += u.p[p01 * 8 + g][t];
        }
        pslc2[p01][m] = a;
    }
    __syncthreads();

    // ---- phase 5: top-k (waves 0,1) + cmp PV via MFMA (all waves, P from fp32 p) ----
    if (w < 2) {
        int p01 = w;
        int sp = p01 ? s1 : s0;
        int cur = sp / SELB;
        float v;
        if (lane < NSEL) {
            int m = lane;
            if (m == 0 || m == cur) v = 1e30f;
            else if (m * SELB <= sp) v = pslc2[p01][m];
            else v = -1e30f;
        } else v = -1e31f;
        unsigned msk = 0;
        #pragma unroll
        for (int pick = 0; pick < TOPN; ++pick) {
            float bv = v;
            #pragma unroll
            for (int o = 32; o > 0; o >>= 1) bv = fmaxf(bv, __shfl_xor(bv, o, 64));
            unsigned long long b = __ballot(v == bv);
            int best = __ffsll((long long)b) - 1;
            if (bv > -5e29f) msk |= 1u << best;
            if (lane == best) v = -1e31f;
        }
        if (lane == 0) selMask[p01] = msk;
    }
    {
        f32x4 o0 = z4, o1 = z4;
        int d0 = w * 32 + l16;
        const short* cvp = &cvfr[((n * 4 + w) * 512 + lane) * 8];   // half=0,kb=0 base
        const float* prow = &u.p[l16][quad * 8];
        #pragma unroll
        for (int kb = 0; kb < 4; ++kb) {
            f32x4 x = *(const f32x4*)(prow + kb * 32);
            f32x4 y = *(const f32x4*)(prow + kb * 32 + 4);
            bf16x8 pa;
            #pragma unroll
            for (int j = 0; j < 4; ++j) { pa[j] = f2bf(x[j]); pa[4+j] = f2bf(y[j]); }
            bf16x8 vb0 = *(const bf16x8*)(cvp + kb * 512);
            bf16x8 vb1 = *(const bf16x8*)(cvp + 2048 + kb * 512);
            o0 = __builtin_amdgcn_mfma_f32_16x16x32_bf16(pa, vb0, o0, 0, 0, 0);
            o1 = __builtin_amdgcn_mfma_f32_16x16x32_bf16(pa, vb1, o1, 0, 0, 0);
        }
        #pragma unroll
        for (int r = 0; r < 4; ++r) {
            int h2 = quad * 4 + r;
            cmpO[h2][d0]      = f2bf(o0[r]);
            cmpO[h2][d0 + 16] = f2bf(o1[r]);
        }
    }
    __syncthreads();

    // ---- phase 6: build union block list ----
    if (tid == 0) {
        unsigned m0 = selMask[0], m1 = selMask[1], mu = m0 | m1;
        int uc = 0;
        for (int b = 0; b < NSEL; ++b)
            if ((mu >> b) & 1u)
                ublk[uc++] = (unsigned)(b * SELB) | (((m0 >> b) & 1u) << 30) | (((m1 >> b) & 1u) << 31);
        shUCnt = uc;
    }
    __syncthreads();
    int uCnt = shUCnt;
    int j00 = (s0 >= WINW) ? (s0 - WINW) : 0;
    int j01 = (s1 >= WINW) ? (s1 - WINW) : 0;
    int tb0 = j00 & ~63;
    int nBlkB = ((s1 - tb0) >> 6) + 1;

    int sLim = (l16 < 8) ? s0 : s1;
    f32x4 o[8];
    f32x4 lacc;

    // swizzled Pw base for this lane's row (l16); 16B-chunk index XORed with (l16&7)
    char* pwRow = (char*)&u.Pw[w][l16][0];
    int swz = l16 & 7;

    // ---- flash chunk loop: coalesced fragment loads, cheap mask, trunc pack ----
    auto run_chunks = [&](int nB, bool selMode) {
        #pragma unroll
        for (int f = 0; f < 8; ++f) o[f] = z4;
        lacc = z4;
        int loWin = selMode ? 0 : ((l16 < 8) ? j00 : j01);
        for (int bi = w; bi < nB; bi += 4) {
            int tstart, vis;
            if (selMode) {
                unsigned e = ublk[bi];
                tstart = (int)(e & 0x0FFFFFFFu);
                vis = (l16 < 8) ? (int)((e >> 30) & 1u) : (int)(e >> 31);
            } else {
                tstart = tb0 + bi * 64;
                vis = 1;
            }
            // scores: 4 token-tiles of 16; K fragments coalesced (log2 domain)
            f32x4 a4[4] = {z4, z4, z4, z4};
            {
                const short* kp = &kfr[((n * 128 + (tstart >> 4)) * 256 + lane) * 8];
                bf16x8 kf[2][4];
                #pragma unroll
                for (int t2 = 0; t2 < 2; ++t2)
                    #pragma unroll
                    for (int kb = 0; kb < 4; ++kb)
                        kf[t2][kb] = *(const bf16x8*)(kp + (t2 * 4 + kb) * 512);
                #pragma unroll
                for (int kb = 0; kb < 4; ++kb) {
                    a4[0] = __builtin_amdgcn_mfma_f32_16x16x32_bf16(kf[0][kb], qb[kb], a4[0], 0, 0, 0);
                    a4[1] = __builtin_amdgcn_mfma_f32_16x16x32_bf16(kf[1][kb], qb[kb], a4[1], 0, 0, 0);
                }
                #pragma unroll
                for (int t2 = 0; t2 < 2; ++t2)
                    #pragma unroll
                    for (int kb = 0; kb < 4; ++kb)
                        kf[t2][kb] = *(const bf16x8*)(kp + ((2 + t2) * 4 + kb) * 512);
                #pragma unroll
                for (int kb = 0; kb < 4; ++kb) {
                    a4[2] = __builtin_amdgcn_mfma_f32_16x16x32_bf16(kf[0][kb], qb[kb], a4[2], 0, 0, 0);
                    a4[3] = __builtin_amdgcn_mfma_f32_16x16x32_bf16(kf[1][kb], qb[kb], a4[3], 0, 0, 0);
                }
            }
            // V first-half prefetch (coalesced fragments)
            const short* vp = &vfr[((n * 32 + (tstart >> 6)) * 1024 + lane) * 8];
            bf16x8 vf[8];
            #pragma unroll
            for (int f = 0; f < 8; ++f) vf[f] = *(const bf16x8*)(vp + f * 512);
            // mask via unsigned-range: valid iff (unsigned)(tloc-lo) < rng; P = 2^a4
            {
                int lo = loWin - tstart;
                int hi = vis ? (sLim - tstart) : (lo - 1);
                int rngS = hi - lo + 1;
                unsigned rng = (unsigned)(rngS > 0 ? rngS : 0);
                int tb = quad * 4 - lo;
                #pragma unroll
                for (int tile = 0; tile < 4; ++tile) {
                    float ev[4];
                    #pragma unroll
                    for (int r = 0; r < 4; ++r) {
                        unsigned uu = (unsigned)(tb + tile * 16 + r);
                        float ex = EXP2(a4[tile][r]);
                        ev[r] = (uu < rng) ? ex : 0.f;
                    }
                    // truncation pack (floor to bf16): 2 ops/pair vs ~5 for RNE
                    unsigned plo = (__float_as_uint(ev[1]) & 0xFFFF0000u) | (__float_as_uint(ev[0]) >> 16);
                    unsigned phi = (__float_as_uint(ev[3]) & 0xFFFF0000u) | (__float_as_uint(ev[2]) >> 16);
                    uint2 pk; pk.x = plo; pk.y = phi;
                    // logical 8B slot: byte = tile*32 + quad*8 -> chunk = tile*2+(quad>>1), half = quad&1
                    int chunk = (tile * 2 + (quad >> 1)) ^ swz;
                    *(uint2*)(pwRow + chunk * 16 + (quad & 1) * 8) = pk;
                }
            }
            __builtin_amdgcn_s_waitcnt(0xC07F);   // lgkmcnt(0): drain Pw writes
            bf16x8 pa0 = *(const bf16x8*)(pwRow + ((quad ^ swz) * 16));
            bf16x8 pa1 = *(const bf16x8*)(pwRow + (((4 + quad) ^ swz) * 16));
            // row-sums via ones-MFMA: lacc[r] = sum_k P[quad*4+r][k] (replaces 12+ VALU adds)
            lacc = __builtin_amdgcn_mfma_f32_16x16x32_bf16(pa0, ones8, lacc, 0, 0, 0);
            lacc = __builtin_amdgcn_mfma_f32_16x16x32_bf16(pa1, ones8, lacc, 0, 0, 0);
            #pragma unroll
            for (int f = 0; f < 8; ++f)
                o[f] = __builtin_amdgcn_mfma_f32_16x16x32_bf16(pa0, vf[f], o[f], 0, 0, 0);
            #pragma unroll
            for (int f = 0; f < 8; ++f)
                o[f] = __builtin_amdgcn_mfma_f32_16x16x32_bf16(pa1, *(const bf16x8*)(vp + (8 + f) * 512), o[f], 0, 0, 0);
        }
    };

    // ---- combine: plain sums (no rescale), 2-step tree over two d-halves ----
    auto combine = [&](bool isA) {
        // lacc[r] holds full row-sum for row quad*4+r (replicated over l16 cols)
        if (l16 == 0) {
            #pragma unroll
            for (int r = 0; r < 4; ++r) lw[w][quad * 4 + r] = lacc[r];
        }
        __syncthreads();   // all chunk loops done; Pw region dead; lw ready
        float ltot = lw[0][l16] + lw[1][l16] + lw[2][l16] + lw[3][l16];
        float linv = 1.f / ltot;
        float linvr[4];
        #pragma unroll
        for (int r = 0; r < 4; ++r) linvr[r] = __shfl(linv, quad * 4 + r, 64);
        #pragma unroll
        for (int half = 0; half < 2; ++half) {
            if (w >= 2) {
                #pragma unroll
                for (int f = 0; f < 4; ++f)
                    #pragma unroll
                    for (int r = 0; r < 4; ++r)
                        u.o2[w - 2][quad * 4 + r][l16 + 16 * f] = o[half * 4 + f][r];
            }
            __syncthreads();
            if (w < 2) {
                #pragma unroll
                for (int f = 0; f < 4; ++f)
                    #pragma unroll
                    for (int r = 0; r < 4; ++r)
                        o[half * 4 + f][r] += u.o2[w][quad * 4 + r][l16 + 16 * f];
            }
            __syncthreads();
            if (w == 1) {
                #pragma unroll
                for (int f = 0; f < 4; ++f)
                    #pragma unroll
                    for (int r = 0; r < 4; ++r)
                        u.o2[0][quad * 4 + r][l16 + 16 * f] = o[half * 4 + f][r];
            }
            __syncthreads();
            if (w == 0) {
                #pragma unroll
                for (int f = 0; f < 4; ++f)
                    #pragma unroll
                    for (int r = 0; r < 4; ++r)
                        o[half * 4 + f][r] += u.o2[0][quad * 4 + r][l16 + 16 * f];
                if (isA) {
                    #pragma unroll
                    for (int f = 0; f < 4; ++f)
                        #pragma unroll
                        for (int r = 0; r < 4; ++r)
                            OselB[quad * 4 + r][l16 + 16 * (half * 4 + f)] = f2bf(o[half * 4 + f][r] * linvr[r]);
                } else {
                    #pragma unroll
                    for (int f = 0; f < 4; ++f)
                        #pragma unroll
                        for (int r = 0; r < 4; ++r) {
                            int h2 = quad * 4 + r;
                            int p = h2 >> 3, g = h2 & 7;
                            int d = l16 + 16 * (half * 4 + f);
                            int ob = ((s0 + p) * HQ + n * GQ + g) * DV + d;
                            float owin = o[half * 4 + f][r] * linvr[r];
                            out[ob] = g3v[h2][0] * bf2f(cmpO[h2][d]) + g3v[h2][1] * bf2f(OselB[h2][d]) + g3v[h2][2] * owin;
                        }
                }
            }
            __syncthreads();   // scratch free before next half / next pass's Pw writes
        }
    };

    run_chunks(uCnt, true);
    combine(true);
    run_chunks(nBlkB, false);
    combine(false);
}

extern "C" void kernel_launch(void* const* d_in, const int* in_sizes, int n_in,
                              void* d_out, int out_size, void* d_ws, size_t ws_size,
                              hipStream_t stream) {
    const float* q   = (const float*)d_in[0];
    const float* k   = (const float*)d_in[1];
    const float* v   = (const float*)d_in[2];
    const float* wck = (const float*)d_in[3];
    const float* wcv = (const float*)d_in[4];
    const float* wg  = (const float*)d_in[5];
    const float* bg  = (const float*)d_in[6];
    float* out = (float*)d_out;

    short* kfr  = (short*)d_ws;                  // 2*128*4*64*8 shorts (1 MB)
    short* vfr  = kfr + 2 * 128 * 4 * 64 * 8;    // 2*32*2*8*64*8 shorts (1 MB)
    short* ckh  = vfr + 2 * 32 * 2 * 8 * 64 * 8; // 2*8*4*64*8 shorts (64 KB)
    short* ckl  = ckh + 2 * 8 * 4 * 64 * 8;      // 64 KB
    short* cvfr = ckl + 2 * 8 * 4 * 64 * 8;      // 2*4*2*4*64*8 shorts (64 KB)
    short* wgh  = cvfr + 2 * 4 * 2 * 4 * 64 * 8; // 4*64*8 shorts (4 KB)
    short* wgl  = wgh + 4 * 64 * 8;              // 4 KB

    k_prep<<<1025, 256, 0, stream>>>(k, v, wck, wcv, wg, kfr, vfr, ckh, ckl, cvfr, wgh, wgl);
    k_fused<<<dim3(SS / 2, HK), 256, 0, stream>>>(q, ckh, ckl, cvfr, kfr, vfr, wgh, wgl, bg, out);
}